// Round 1
// baseline (6145.424 us; speedup 1.0000x reference)
//
#include <hip/hip_runtime.h>
#include <math.h>

// ---------------------------------------------------------------------------
// Fused NeRF MLP, round 1: correctness + bf16-numerics-parity baseline.
// Weights pre-rounded to bf16 (packed in d_ws by a prologue kernel);
// activations stored as bf16 in LDS; all accumulation in fp32 VALU.
// Each 64-lane wave independently processes 16 points through all 9 layers.
// No barriers: per-wave p-slices of LDS are disjoint, and each wave finishes
// all LDS reads of a layer (program order) before overwriting in place.
// ---------------------------------------------------------------------------

struct WPtrs { const float* w[8]; };
struct BPtrs { const float* b[8]; };

// RNE float -> bf16 bits (matches __float2bfloat16 / MFMA input rounding)
__device__ __forceinline__ unsigned short f2bf(float v) {
  unsigned u = __float_as_uint(v);
  u = u + 0x7fffu + ((u >> 16) & 1u);
  return (unsigned short)(u >> 16);
}
__device__ __forceinline__ float bf_lo(unsigned u) { return __uint_as_float(u << 16); }
__device__ __forceinline__ float bf_hi(unsigned u) { return __uint_as_float(u & 0xffff0000u); }
__device__ __forceinline__ unsigned pk2(float a, float b) {
  return (unsigned)f2bf(a) | ((unsigned)f2bf(b) << 16);
}

// ---------------------------------------------------------------------------
// Prologue: pack all 8 hidden-layer weight matrices into bf16, K-padded, with
// column swizzle so lane l's 4 columns {l, l+64, l+128, l+192} are contiguous
// (one dwordx2 per lane per k-row in the main loop).
// Padded K rows per layer: {64,256,256,256,256,320,256,256} -> 1920 rows.
// Row offsets: L0:0 L1:64 L2:320 L3:576 L4:832 L5:1088 (segB at 1344) L6:1408 L7:1664
// ---------------------------------------------------------------------------
__global__ void pack_weights(WPtrs W, unsigned short* __restrict__ out) {
  int idx = blockIdx.x * 256 + threadIdx.x;
  if (idx >= 1920 * 256) return;
  int row = idx >> 8;
  int c   = idx & 255;        // packed col position = lane*4 + jt
  int lane = c >> 2, jt = c & 3;
  int j = lane + (jt << 6);   // original output column
  int l, k;
  if      (row < 64)   { l = 0; k = row; }
  else if (row < 320)  { l = 1; k = row - 64; }
  else if (row < 576)  { l = 2; k = row - 320; }
  else if (row < 832)  { l = 3; k = row - 576; }
  else if (row < 1088) { l = 4; k = row - 832; }
  else if (row < 1408) { l = 5; k = row - 1088; }
  else if (row < 1664) { l = 6; k = row - 1408; }
  else                 { l = 7; k = row - 1664; }
  const int realK[8] = {63, 256, 256, 256, 256, 319, 256, 256};
  float v = (k < realK[l]) ? W.w[l][k * 256 + j] : 0.0f;
  out[idx] = f2bf(v);
}

// ---------------------------------------------------------------------------
// One K-segment of a layer: acc[4][16] += W[k][cols] * x[k][points]
// src: bf16 LDS activations, layout [k][64 points], this wave reads its own
//      16-point slice (wave-uniform address -> LDS broadcast, conflict-free).
// ---------------------------------------------------------------------------
template <bool PACKED>
__device__ __forceinline__ void process_seg(
    const unsigned short* src, int kRows,
    const unsigned short* __restrict__ wp,   // packed bf16 rows (PACKED)
    const float* __restrict__ wr,            // raw fp32 rows (!PACKED fallback)
    int lane, int ps, float acc[4][16]) {
#pragma unroll 4
  for (int k = 0; k < kRows; ++k) {
    float w0, w1, w2, w3;
    if (PACKED) {
      uint2 wu = *reinterpret_cast<const uint2*>(wp + ((k << 8) + (lane << 2)));
      w0 = bf_lo(wu.x); w1 = bf_hi(wu.x);
      w2 = bf_lo(wu.y); w3 = bf_hi(wu.y);
    } else {
      const float* p = wr + k * 256 + lane;
      w0 = p[0]; w1 = p[64]; w2 = p[128]; w3 = p[192];
    }
    const uint4* xr = reinterpret_cast<const uint4*>(src + ((k << 6) + ps));
    uint4 q0 = xr[0];
    uint4 q1 = xr[1];
    float x[16];
    x[0]  = bf_lo(q0.x); x[1]  = bf_hi(q0.x);
    x[2]  = bf_lo(q0.y); x[3]  = bf_hi(q0.y);
    x[4]  = bf_lo(q0.z); x[5]  = bf_hi(q0.z);
    x[6]  = bf_lo(q0.w); x[7]  = bf_hi(q0.w);
    x[8]  = bf_lo(q1.x); x[9]  = bf_hi(q1.x);
    x[10] = bf_lo(q1.y); x[11] = bf_hi(q1.y);
    x[12] = bf_lo(q1.z); x[13] = bf_hi(q1.z);
    x[14] = bf_lo(q1.w); x[15] = bf_hi(q1.w);
#pragma unroll
    for (int pp = 0; pp < 16; ++pp) {
      acc[0][pp] = fmaf(w0, x[pp], acc[0][pp]);
      acc[1][pp] = fmaf(w1, x[pp], acc[1][pp]);
      acc[2][pp] = fmaf(w2, x[pp], acc[2][pp]);
      acc[3][pp] = fmaf(w3, x[pp], acc[3][pp]);
    }
  }
}

template <bool PACKED>
__device__ __forceinline__ void run_layer(
    const unsigned short* srcA, int kA,
    const unsigned short* srcB, int kB,          // skip-concat segment (or null)
    const unsigned short* __restrict__ wpA,
    const unsigned short* __restrict__ wpB,
    const float* __restrict__ wrA,
    const float* __restrict__ wrB,
    const float* __restrict__ bias,
    unsigned short* dst, int lane, int ps) {
  float acc[4][16];
#pragma unroll
  for (int jt = 0; jt < 4; ++jt) {
    float bb = bias[lane + (jt << 6)];
#pragma unroll
    for (int pp = 0; pp < 16; ++pp) acc[jt][pp] = bb;
  }
  process_seg<PACKED>(srcA, kA, wpA, wrA, lane, ps, acc);
  if (srcB) process_seg<PACKED>(srcB, kB, wpB, wrB, lane, ps, acc);
  // relu + round-to-bf16 + in-place writeback (all reads above already done)
#pragma unroll
  for (int jt = 0; jt < 4; ++jt) {
    unsigned short* dr = dst + (((lane + (jt << 6)) << 6) + ps);
    float r[16];
#pragma unroll
    for (int pp = 0; pp < 16; ++pp) r[pp] = fmaxf(acc[jt][pp], 0.0f);
    uint4 a, b;
    a.x = pk2(r[0],  r[1]);  a.y = pk2(r[2],  r[3]);
    a.z = pk2(r[4],  r[5]);  a.w = pk2(r[6],  r[7]);
    b.x = pk2(r[8],  r[9]);  b.y = pk2(r[10], r[11]);
    b.z = pk2(r[12], r[13]); b.w = pk2(r[14], r[15]);
    reinterpret_cast<uint4*>(dr)[0] = a;
    reinterpret_cast<uint4*>(dr)[1] = b;
  }
}

template <bool PACKED>
__launch_bounds__(256, 2)
__global__ void mlp_fused(const float* __restrict__ pts, int N,
                          WPtrs W, BPtrs B,
                          const float* __restrict__ w8,
                          const float* __restrict__ b8,
                          const unsigned short* __restrict__ wpk,
                          float* __restrict__ out) {
  __shared__ unsigned short act[256 * 64];  // [k][p] bf16, 32 KB
  __shared__ unsigned short emb[64 * 64];   // [f][p] bf16 (f=63 row zero), 8 KB
  const int lane = threadIdx.x & 63;
  const int ps   = (threadIdx.x >> 6) << 4;           // this wave's 16-pt slice
  const long pbase = (long)blockIdx.x * 64 + ps;      // first global point

  // ---- positional embedding: f = d*21 + {id, sin(2^i), cos(2^i)} ----------
#pragma unroll
  for (int i = 0; i < 16; ++i) {
    int idx = (i << 6) + lane;   // 64 features x 16 points
    int f = idx >> 4;
    int pp = idx & 15;
    float v = 0.0f;
    if (f < 63) {
      int d = f / 21;
      int r = f - d * 21;
      float c = (pbase + pp < N) ? pts[(pbase + pp) * 3 + d] : 0.0f;
      if (r == 0)       v = c;
      else if (r <= 10) v = sinf(c * (float)(1 << (r - 1)));
      else              v = cosf(c * (float)(1 << (r - 11)));
    }
    emb[(f << 6) + ps + pp] = f2bf(v);
  }
  // no barrier needed: each wave only touches its own p-slice, in order

  // ---- layer 0: emb(63) -> 256 --------------------------------------------
  run_layer<PACKED>(emb, PACKED ? 64 : 63, nullptr, 0,
                    wpk, nullptr, W.w[0], nullptr, B.b[0], act, lane, ps);
  // ---- layers 1..4: 256 -> 256 --------------------------------------------
#pragma unroll 1
  for (int l = 1; l <= 4; ++l) {
    run_layer<PACKED>(act, 256, nullptr, 0,
                      wpk + (64 + (l - 1) * 256) * 256, nullptr,
                      W.w[l], nullptr, B.b[l], act, lane, ps);
  }
  // ---- layer 5: concat(x,emb)(319) -> 256 ---------------------------------
  run_layer<PACKED>(act, 256, emb, PACKED ? 64 : 63,
                    wpk + 1088 * 256, wpk + 1344 * 256,
                    W.w[5], W.w[5] + 256 * 256, B.b[5], act, lane, ps);
  // ---- layers 6..7: 256 -> 256 --------------------------------------------
#pragma unroll 1
  for (int l = 6; l <= 7; ++l) {
    run_layer<PACKED>(act, 256, nullptr, 0,
                      wpk + (1408 + (l - 6) * 256) * 256, nullptr,
                      W.w[l], nullptr, B.b[l], act, lane, ps);
  }
  // ---- final layer: 256 -> 4 (fp32 weights, no relu) ----------------------
  {
    const int pp = lane & 15;
    const int cc = lane >> 4;
    float a = b8[cc];
#pragma unroll 4
    for (int k = 0; k < 256; ++k) {
      float xv = bf_lo((unsigned)act[(k << 6) + ps + pp]);
      a = fmaf(xv, w8[(k << 2) + cc], a);
    }
    if (pbase + pp < N) out[(pbase + pp) * 4 + cc] = a;
  }
}

extern "C" void kernel_launch(void* const* d_in, const int* in_sizes, int n_in,
                              void* d_out, int out_size, void* d_ws, size_t ws_size,
                              hipStream_t stream) {
  const float* pts = (const float*)d_in[0];
  WPtrs W; BPtrs B;
  for (int i = 0; i < 8; ++i) {
    W.w[i] = (const float*)d_in[1 + 2 * i];
    B.b[i] = (const float*)d_in[2 + 2 * i];
  }
  const float* w8 = (const float*)d_in[17];
  const float* b8 = (const float*)d_in[18];
  float* out = (float*)d_out;
  const int N = in_sizes[0] / 3;
  const int nblocks = (N + 63) / 64;

  const size_t need = (size_t)1920 * 256 * sizeof(unsigned short);  // 0.94 MB
  if (ws_size >= need) {
    unsigned short* wpk = (unsigned short*)d_ws;
    pack_weights<<<1920, 256, 0, stream>>>(W, wpk);
    mlp_fused<true><<<nblocks, 256, 0, stream>>>(pts, N, W, B, w8, b8, wpk, out);
  } else {
    // fallback: read fp32 weights directly (more accurate, slower inner loop)
    mlp_fused<false><<<nblocks, 256, 0, stream>>>(pts, N, W, B, w8, b8, nullptr, out);
  }
}

// Round 2
// 676.634 us; speedup vs baseline: 9.0823x; 9.0823x over previous
//
#include <hip/hip_runtime.h>
#include <math.h>

// ---------------------------------------------------------------------------
// Round 2: MFMA (16x16x32 bf16) fused NeRF MLP.
// Per block: 128-point tile, 4 waves; wave w owns output channels [64w,64w+64).
// Activations: LDS bf16 [pt][ch], XOR-swizzled ( ^ (pt&7)*16 bytes ) so
// B-frag ds_read_b128 and D ds_write_b64 are 2-way bank aliased only (free).
// Weights: prepacked bf16 [out_ch][K_pad] in d_ws -> A-frag = one dwordx4.
// Numerics identical to round 1 (bf16 weights+acts, fp32 accumulate): proven
// absmax 4.15e-3 vs threshold 1.148e-2.
// ---------------------------------------------------------------------------

typedef __attribute__((ext_vector_type(8))) short short8;
typedef __attribute__((ext_vector_type(4))) float f32x4;

struct WPtrs { const float* w[8]; };
struct BPtrs { const float* b[8]; };

__device__ __forceinline__ unsigned short f2bf(float v) {
  unsigned u = __float_as_uint(v);
  u = u + 0x7fffu + ((u >> 16) & 1u);
  return (unsigned short)(u >> 16);
}
__device__ __forceinline__ float bf_lo(unsigned u) { return __uint_as_float(u << 16); }
__device__ __forceinline__ float bf_hi(unsigned u) { return __uint_as_float(u & 0xffff0000u); }
__device__ __forceinline__ unsigned pk2(float a, float b) {
  return (unsigned)f2bf(a) | ((unsigned)f2bf(b) << 16);
}

// packed-weight element offsets (bf16 elements)
#define PK_L0 0
#define PK_L1 16384
#define PK_L2 81920
#define PK_L3 147456
#define PK_L4 212992
#define PK_L5 278528
#define PK_L6 360448
#define PK_L7 425984
#define PK_W8 491520
#define PK_TOTAL 495616   // = 1936 * 256

// ---------------------------------------------------------------------------
// Prologue: W^T pack. layout per layer: [j=out_ch 0..255][k=0..Kpad-1], bf16.
// w8 packed as [j=0..15 (4 real)][k=0..255].
// ---------------------------------------------------------------------------
__global__ void pack_weights(WPtrs W, const float* __restrict__ w8,
                             unsigned short* __restrict__ out) {
  int idx = blockIdx.x * 256 + threadIdx.x;
  if (idx >= PK_TOTAL) return;
  float v;
  if (idx >= PK_W8) {
    int t = idx - PK_W8;
    int j = t >> 8, k = t & 255;
    v = (j < 4) ? w8[k * 4 + j] : 0.0f;
  } else {
    int l, base, kpad, realk;
    if      (idx < PK_L1) { l = 0; base = PK_L0; kpad = 64;  realk = 63;  }
    else if (idx < PK_L2) { l = 1; base = PK_L1; kpad = 256; realk = 256; }
    else if (idx < PK_L3) { l = 2; base = PK_L2; kpad = 256; realk = 256; }
    else if (idx < PK_L4) { l = 3; base = PK_L3; kpad = 256; realk = 256; }
    else if (idx < PK_L5) { l = 4; base = PK_L4; kpad = 256; realk = 256; }
    else if (idx < PK_L6) { l = 5; base = PK_L5; kpad = 320; realk = 319; }
    else if (idx < PK_L7) { l = 6; base = PK_L6; kpad = 256; realk = 256; }
    else                  { l = 7; base = PK_L7; kpad = 256; realk = 256; }
    int t = idx - base;
    int j = t / kpad, k = t - j * kpad;
    v = (k < realk) ? W.w[l][k * 256 + j] : 0.0f;
  }
  out[idx] = f2bf(v);
}

__device__ __forceinline__ f32x4 mfma16(short8 a, short8 b, f32x4 c) {
  return __builtin_amdgcn_mfma_f32_16x16x32_bf16(a, b, c, 0, 0, 0);
}

__device__ __forceinline__ float embf(int f, float c0, float c1, float c2) {
  if (f >= 63) return 0.0f;
  int d = f / 21;
  int r = f - d * 21;
  float x = (d == 0) ? c0 : (d == 1 ? c1 : c2);
  if (r == 0) return x;
  if (r <= 10) return sinf(x * (float)(1 << (r - 1)));
  return cosf(x * (float)(1 << (r - 11)));
}

// One layer: acc[4][8] over {A: packed W^T global, B: swizzled LDS}, then
// relu+bf16 writeback to dst. KKA chunks (of 32 ch) from srcA (row RBA bytes),
// KKB chunks from srcB (emb, 128B rows). Two barriers: reads-done, writes-done.
template <int KKA, int KKB, int RBA>
__device__ __forceinline__ void do_layer(
    const unsigned short* srcA, const unsigned short* srcB,
    const unsigned short* __restrict__ wbase0,
    const float* __restrict__ bias,
    unsigned short* dst, int w, int lane) {
  constexpr int KK = KKA + KKB;
  constexpr int KPAD = KK * 32;
  const int quad = lane >> 4, l16 = lane & 15;
  const unsigned swz = (unsigned)((l16 & 7) << 4);

  f32x4 acc[4][8];
#pragma unroll
  for (int mt = 0; mt < 4; ++mt) {
    f32x4 bv = *reinterpret_cast<const f32x4*>(bias + w * 64 + mt * 16 + quad * 4);
#pragma unroll
    for (int nt = 0; nt < 8; ++nt) acc[mt][nt] = bv;
  }

  const unsigned short* wb = wbase0 + (w * 64 + l16) * KPAD + quad * 8;

#pragma unroll 1
  for (int kk = 0; kk < KK; ++kk) {
    short8 af[4];
#pragma unroll
    for (int mt = 0; mt < 4; ++mt)
      af[mt] = *reinterpret_cast<const short8*>(wb + mt * 16 * KPAD + kk * 32);
    const unsigned short* src; int rb, kloc;
    if (KKB > 0 && kk >= KKA) { src = srcB; rb = 128; kloc = kk - KKA; }
    else                      { src = srcA; rb = RBA; kloc = kk; }
    const unsigned chunk = ((unsigned)(kloc * 64 + quad * 16)) ^ swz;
    short8 bf[8];
#pragma unroll
    for (int nt = 0; nt < 8; ++nt)
      bf[nt] = *reinterpret_cast<const short8*>(
          (const char*)src + (unsigned)((nt * 16 + l16) * rb) + chunk);
#pragma unroll
    for (int mt = 0; mt < 4; ++mt)
#pragma unroll
      for (int nt = 0; nt < 8; ++nt)
        acc[mt][nt] = mfma16(af[mt], bf[nt], acc[mt][nt]);
  }
  __syncthreads();   // all waves done reading src
#pragma unroll
  for (int nt = 0; nt < 8; ++nt) {
    char* rowp = (char*)dst + (unsigned)((nt * 16 + l16) * 512);
#pragma unroll
    for (int mt = 0; mt < 4; ++mt) {
      unsigned off = ((unsigned)((w * 64 + mt * 16 + quad * 4) * 2)) ^ swz;
      f32x4 v = acc[mt][nt];
      uint2 pkd;
      pkd.x = pk2(fmaxf(v.x, 0.0f), fmaxf(v.y, 0.0f));
      pkd.y = pk2(fmaxf(v.z, 0.0f), fmaxf(v.w, 0.0f));
      *reinterpret_cast<uint2*>(rowp + off) = pkd;
    }
  }
  __syncthreads();   // all writes visible
}

__launch_bounds__(256, 2)
__global__ void mlp_mfma(const float* __restrict__ pts, long N,
                         BPtrs B, const float* __restrict__ b8,
                         const unsigned short* __restrict__ wpk,
                         float* __restrict__ out) {
  __shared__ unsigned short act[128 * 256];  // 64 KB, swizzled [pt][ch]
  __shared__ unsigned short emb[128 * 64];   // 16 KB, swizzled [pt][f]
  const int tid = threadIdx.x;
  const int w = tid >> 6, lane = tid & 63;
  const long pbase = (long)blockIdx.x * 128;

  // ---- embedding: thread t -> point t/2, features (t&1)*32..+31 ------------
  {
    const int pt = tid >> 1;
    const int f0base = (tid & 1) * 32;
    const long pg = pbase + pt;
    float c0 = 0.f, c1 = 0.f, c2 = 0.f;
    if (pg < N) { c0 = pts[pg * 3]; c1 = pts[pg * 3 + 1]; c2 = pts[pg * 3 + 2]; }
    const unsigned swz = (unsigned)((pt & 7) << 4);
    char* rowp = (char*)emb + (unsigned)(pt * 128);
#pragma unroll
    for (int i = 0; i < 32; i += 2) {
      int f0 = f0base + i;
      float v0 = embf(f0, c0, c1, c2);
      float v1 = embf(f0 + 1, c0, c1, c2);
      *reinterpret_cast<unsigned*>(rowp + (((unsigned)(f0 * 2)) ^ swz)) = pk2(v0, v1);
    }
  }
  __syncthreads();

  do_layer<2, 0, 128>(emb, nullptr, wpk + PK_L0, B.b[0], act, w, lane);
  do_layer<8, 0, 512>(act, nullptr, wpk + PK_L1, B.b[1], act, w, lane);
  do_layer<8, 0, 512>(act, nullptr, wpk + PK_L2, B.b[2], act, w, lane);
  do_layer<8, 0, 512>(act, nullptr, wpk + PK_L3, B.b[3], act, w, lane);
  do_layer<8, 0, 512>(act, nullptr, wpk + PK_L4, B.b[4], act, w, lane);
  do_layer<8, 2, 512>(act, emb,     wpk + PK_L5, B.b[5], act, w, lane);
  do_layer<8, 0, 512>(act, nullptr, wpk + PK_L6, B.b[6], act, w, lane);
  do_layer<8, 0, 512>(act, nullptr, wpk + PK_L7, B.b[7], act, w, lane);

  // ---- final 256->4 via MFMA (W8^T zero-padded to 16 rows) -----------------
  {
    const int quad = lane >> 4, l16 = lane & 15;
    const unsigned swz = (unsigned)((l16 & 7) << 4);
    f32x4 acc0 = {0.f, 0.f, 0.f, 0.f}, acc1 = acc0;
    const unsigned short* w8b = wpk + PK_W8 + l16 * 256 + quad * 8;
    const int pt0 = 32 * w + l16;     // wave w covers points [32w, 32w+32)
    const int pt1 = pt0 + 16;
#pragma unroll 2
    for (int kk = 0; kk < 8; ++kk) {
      short8 a = *reinterpret_cast<const short8*>(w8b + kk * 32);
      const unsigned chunk = ((unsigned)(kk * 64 + quad * 16)) ^ swz;
      short8 b0 = *reinterpret_cast<const short8*>(
          (const char*)act + (unsigned)(pt0 * 512) + chunk);
      short8 b1 = *reinterpret_cast<const short8*>(
          (const char*)act + (unsigned)(pt1 * 512) + chunk);
      acc0 = mfma16(a, b0, acc0);
      acc1 = mfma16(a, b1, acc1);
    }
    if (quad == 0) {   // D rows 0..3 = real output channels
      f32x4 bb = *reinterpret_cast<const f32x4*>(b8);
      long pg0 = pbase + pt0, pg1 = pbase + pt1;
      f32x4 v0 = acc0 + bb, v1 = acc1 + bb;
      if (pg0 < N) *reinterpret_cast<f32x4*>(out + pg0 * 4) = v0;
      if (pg1 < N) *reinterpret_cast<f32x4*>(out + pg1 * 4) = v1;
    }
  }
}

// ---------------------------------------------------------------------------
// Fallback (ws too small): round-1 VALU kernel, fp32 weights, proven correct.
// ---------------------------------------------------------------------------
__device__ __forceinline__ void fb_seg(const unsigned short* src, int kRows,
                                       const float* __restrict__ wr,
                                       int lane, int ps, float acc[4][16]) {
#pragma unroll 4
  for (int k = 0; k < kRows; ++k) {
    const float* p = wr + k * 256 + lane;
    float w0 = p[0], w1 = p[64], w2 = p[128], w3 = p[192];
    const uint4* xr = reinterpret_cast<const uint4*>(src + ((k << 6) + ps));
    uint4 q0 = xr[0], q1 = xr[1];
    float x[16];
    x[0] = bf_lo(q0.x);  x[1] = bf_hi(q0.x);  x[2] = bf_lo(q0.y);  x[3] = bf_hi(q0.y);
    x[4] = bf_lo(q0.z);  x[5] = bf_hi(q0.z);  x[6] = bf_lo(q0.w);  x[7] = bf_hi(q0.w);
    x[8] = bf_lo(q1.x);  x[9] = bf_hi(q1.x);  x[10] = bf_lo(q1.y); x[11] = bf_hi(q1.y);
    x[12] = bf_lo(q1.z); x[13] = bf_hi(q1.z); x[14] = bf_lo(q1.w); x[15] = bf_hi(q1.w);
#pragma unroll
    for (int pp = 0; pp < 16; ++pp) {
      acc[0][pp] = fmaf(w0, x[pp], acc[0][pp]);
      acc[1][pp] = fmaf(w1, x[pp], acc[1][pp]);
      acc[2][pp] = fmaf(w2, x[pp], acc[2][pp]);
      acc[3][pp] = fmaf(w3, x[pp], acc[3][pp]);
    }
  }
}

__device__ __forceinline__ void fb_layer(const unsigned short* srcA, int kA,
                                         const unsigned short* srcB, int kB,
                                         const float* wrA, const float* wrB,
                                         const float* bias,
                                         unsigned short* dst, int lane, int ps) {
  float acc[4][16];
#pragma unroll
  for (int jt = 0; jt < 4; ++jt) {
    float bb = bias[lane + (jt << 6)];
#pragma unroll
    for (int pp = 0; pp < 16; ++pp) acc[jt][pp] = bb;
  }
  fb_seg(srcA, kA, wrA, lane, ps, acc);
  if (srcB) fb_seg(srcB, kB, wrB, lane, ps, acc);
#pragma unroll
  for (int jt = 0; jt < 4; ++jt) {
    unsigned short* dr = dst + (((lane + (jt << 6)) << 6) + ps);
    float r[16];
#pragma unroll
    for (int pp = 0; pp < 16; ++pp) r[pp] = fmaxf(acc[jt][pp], 0.0f);
    uint4 a, b;
    a.x = pk2(r[0], r[1]);   a.y = pk2(r[2], r[3]);
    a.z = pk2(r[4], r[5]);   a.w = pk2(r[6], r[7]);
    b.x = pk2(r[8], r[9]);   b.y = pk2(r[10], r[11]);
    b.z = pk2(r[12], r[13]); b.w = pk2(r[14], r[15]);
    reinterpret_cast<uint4*>(dr)[0] = a;
    reinterpret_cast<uint4*>(dr)[1] = b;
  }
}

__launch_bounds__(256, 2)
__global__ void mlp_fallback(const float* __restrict__ pts, int N,
                             WPtrs W, BPtrs B,
                             const float* __restrict__ w8,
                             const float* __restrict__ b8,
                             float* __restrict__ out) {
  __shared__ unsigned short act[256 * 64];
  __shared__ unsigned short emb[64 * 64];
  const int lane = threadIdx.x & 63;
  const int ps = (threadIdx.x >> 6) << 4;
  const long pbase = (long)blockIdx.x * 64 + ps;
#pragma unroll
  for (int i = 0; i < 16; ++i) {
    int idx = (i << 6) + lane;
    int f = idx >> 4, pp = idx & 15;
    float v = 0.0f;
    if (f < 63) {
      float c = (pbase + pp < N) ? pts[(pbase + pp) * 3 + (f / 21)] : 0.0f;
      v = embf(f, (f / 21 == 0) ? c : 0.f, (f / 21 == 1) ? c : 0.f,
               (f / 21 == 2) ? c : 0.f);
    }
    emb[(f << 6) + ps + pp] = f2bf(v);
  }
  fb_layer(emb, 63, nullptr, 0, W.w[0], nullptr, B.b[0], act, lane, ps);
#pragma unroll 1
  for (int l = 1; l <= 4; ++l)
    fb_layer(act, 256, nullptr, 0, W.w[l], nullptr, B.b[l], act, lane, ps);
  fb_layer(act, 256, emb, 63, W.w[5], W.w[5] + 256 * 256, B.b[5], act, lane, ps);
#pragma unroll 1
  for (int l = 6; l <= 7; ++l)
    fb_layer(act, 256, nullptr, 0, W.w[l], nullptr, B.b[l], act, lane, ps);
  {
    const int pp = lane & 15, cc = lane >> 4;
    float a = b8[cc];
#pragma unroll 4
    for (int k = 0; k < 256; ++k)
      a = fmaf(bf_lo((unsigned)act[(k << 6) + ps + pp]), w8[(k << 2) + cc], a);
    if (pbase + pp < N) out[(pbase + pp) * 4 + cc] = a;
  }
}

extern "C" void kernel_launch(void* const* d_in, const int* in_sizes, int n_in,
                              void* d_out, int out_size, void* d_ws, size_t ws_size,
                              hipStream_t stream) {
  const float* pts = (const float*)d_in[0];
  WPtrs W; BPtrs B;
  for (int i = 0; i < 8; ++i) {
    W.w[i] = (const float*)d_in[1 + 2 * i];
    B.b[i] = (const float*)d_in[2 + 2 * i];
  }
  const float* w8 = (const float*)d_in[17];
  const float* b8 = (const float*)d_in[18];
  float* out = (float*)d_out;
  const long N = in_sizes[0] / 3;

  const size_t need = (size_t)PK_TOTAL * sizeof(unsigned short);  // ~0.95 MB
  if (ws_size >= need) {
    unsigned short* wpk = (unsigned short*)d_ws;
    pack_weights<<<1936, 256, 0, stream>>>(W, w8, wpk);
    mlp_mfma<<<(int)((N + 127) / 128), 256, 0, stream>>>(pts, N, B, b8, wpk, out);
  } else {
    mlp_fallback<<<(int)((N + 63) / 64), 256, 0, stream>>>(pts, (int)N, W, B, w8, b8, out);
  }
}

// Round 3
// 621.059 us; speedup vs baseline: 9.8951x; 1.0895x over previous
//
#include <hip/hip_runtime.h>
#include <math.h>

// ---------------------------------------------------------------------------
// Round 3: 64-pt tile, 3 blocks/CU, adds-only padded-row LDS (no XOR, no bank
// conflicts), HW bf16 pack (v_cvt_pk_bf16_f32 when available), HW v_sin
// embedding. Numerics = round 2 (bf16 W+act, fp32 acc): absmax 3.9e-3 proven.
// Wave w owns out-channels [64w, 64w+64); acc = 4mt x 4nt f32x4.
// A-pack layout: [kk-block][ch 0..255][32 elems] -> SGPR-friendly addressing.
// ---------------------------------------------------------------------------

typedef __attribute__((ext_vector_type(8))) short short8;
typedef __attribute__((ext_vector_type(4))) float f32x4;

struct WPtrs { const float* w[8]; };
struct BPtrs { const float* b[8]; };

#define INV2PI 0.15915494309189533577f

// act rows: 264 elems (528 B = 132 dwords == 4 mod 32 -> bank rotation)
#define ACT_PITCH 264
// emb rows: 72 elems (144 B = 36 dwords == 4 mod 32)
#define EMB_PITCH 72

// kk-block offsets (elems = kkg * 8192): L0@0 (2kk) L1@2 L2@10 L3@18 L4@26
// L5@34 (10kk incl emb) L6@44 L7@52 ; total 60 kk-blocks.
#define PK_L0 0
#define PK_L1 16384
#define PK_L2 81920
#define PK_L3 147456
#define PK_L4 212992
#define PK_L5 278528
#define PK_L6 360448
#define PK_L7 425984
#define PK_W8 491520           // [j=0..15][k=0..255]
#define PK_TOTAL 495616

__device__ __forceinline__ unsigned short f2bf(float v) {
  unsigned u = __float_as_uint(v);
  u = u + 0x7fffu + ((u >> 16) & 1u);
  return (unsigned short)(u >> 16);
}
__device__ __forceinline__ float bf_lo(unsigned u) { return __uint_as_float(u << 16); }
__device__ __forceinline__ float bf_hi(unsigned u) { return __uint_as_float(u & 0xffff0000u); }

// pack two fp32 -> packed bf16 pair (RNE), low half = a
__device__ __forceinline__ unsigned cvtpk(float a, float b) {
#if __has_builtin(__builtin_amdgcn_cvt_pk_bf16_f32)
  typedef __attribute__((ext_vector_type(2))) __bf16 bf16x2_t;
  bf16x2_t r = __builtin_amdgcn_cvt_pk_bf16_f32(a, b);
  return __builtin_bit_cast(unsigned, r);
#else
  unsigned ua = __float_as_uint(a);
  ua += 0x7fffu + ((ua >> 16) & 1u);
  unsigned ub = __float_as_uint(b);
  ub += 0x7fffu + ((ub >> 16) & 1u);
#if __has_builtin(__builtin_amdgcn_perm)
  return __builtin_amdgcn_perm(ub, ua, 0x07060302u);  // [ub.hi16 | ua.hi16]
#else
  return (ua >> 16) | (ub & 0xffff0000u);
#endif
#endif
}

__device__ __forceinline__ float fractf_(float x) {
#if __has_builtin(__builtin_amdgcn_fract_f32)
  return __builtin_amdgcn_fract_f32(x);
#else
  return x - floorf(x);
#endif
}
__device__ __forceinline__ float sin_rev(float rev) {  // sin(2*pi*rev)
#if __has_builtin(__builtin_amdgcn_sinf)
  return __builtin_amdgcn_sinf(rev);
#else
  return __sinf(rev * 6.283185307179586f);
#endif
}

// feature value: f = d*21 + {id, sin(2^0..2^9 x), cos(2^0..2^9 x)}
__device__ __forceinline__ float embval(int f, float c0, float c1, float c2,
                                        float x0, float x1, float x2) {
  if (f >= 63) return 0.0f;
  int d = (f >= 21 ? 1 : 0) + (f >= 42 ? 1 : 0);
  int r = f - d * 21;
  float c = (d == 0) ? c0 : (d == 1 ? c1 : c2);
  float x = (d == 0) ? x0 : (d == 1 ? x1 : x2);  // c/(2*pi)
  bool isc = r > 10;
  int e = isc ? (r - 11) : (r - 1);
  float rev = fractf_(ldexpf(x, e) + (isc ? 0.25f : 0.0f));
  float s = sin_rev(rev);
  return (r == 0) ? c : s;
}

__device__ __forceinline__ f32x4 mfma16(short8 a, short8 b, f32x4 c) {
  return __builtin_amdgcn_mfma_f32_16x16x32_bf16(a, b, c, 0, 0, 0);
}

// ---------------------------------------------------------------------------
// Prologue: pack weights into [kk][ch][32] bf16 blocks (+ W8 as [j16][k256]).
// ---------------------------------------------------------------------------
__global__ void pack_weights(WPtrs W, const float* __restrict__ w8,
                             unsigned short* __restrict__ out) {
  int idx = blockIdx.x * 256 + threadIdx.x;
  if (idx >= PK_TOTAL) return;
  float v;
  if (idx >= PK_W8) {
    int t = idx - PK_W8;
    int j = t >> 8, k = t & 255;
    v = (j < 4) ? w8[k * 4 + j] : 0.0f;
  } else {
    int e = idx & 31;
    int blk = idx >> 5;
    int kkg = blk >> 8;
    int ch = blk & 255;
    int l, kk0;
    if      (kkg < 2)  { l = 0; kk0 = 0;  }
    else if (kkg < 10) { l = 1; kk0 = 2;  }
    else if (kkg < 18) { l = 2; kk0 = 10; }
    else if (kkg < 26) { l = 3; kk0 = 18; }
    else if (kkg < 34) { l = 4; kk0 = 26; }
    else if (kkg < 44) { l = 5; kk0 = 34; }
    else if (kkg < 52) { l = 6; kk0 = 44; }
    else               { l = 7; kk0 = 52; }
    int k = (kkg - kk0) * 32 + e;
    const int realK[8] = {63, 256, 256, 256, 256, 319, 256, 256};
    v = (k < realK[l]) ? W.w[l][k * 256 + ch] : 0.0f;
  }
  out[idx] = f2bf(v);
}

// ---------------------------------------------------------------------------
// One layer. A: global packed blocks (8192-elem kk stride, 512-elem mt
// stride -> imm offsets). B: LDS, padded-pitch rows, kk advances by +32 elems.
// ---------------------------------------------------------------------------
template <int KKA, int PA, int KKB, bool RB>
__device__ __forceinline__ void do_layer(
    const unsigned short* srcA, const unsigned short* srcB,
    const unsigned short* __restrict__ wblk,
    const float* __restrict__ bias,
    unsigned short* dst, int w, int quad, int l16) {
  f32x4 acc[4][4];
#pragma unroll
  for (int mt = 0; mt < 4; ++mt) {
    f32x4 bv = *reinterpret_cast<const f32x4*>(bias + w * 64 + mt * 16 + quad * 4);
#pragma unroll
    for (int nt = 0; nt < 4; ++nt) acc[mt][nt] = bv;
  }

  const unsigned short* ab = wblk + (unsigned)((w * 64 + l16) * 32 + quad * 8);
  const unsigned short* ba = srcA + (unsigned)(l16 * PA + quad * 8);

#pragma unroll 2
  for (int kk = 0; kk < KKA; ++kk) {
    short8 af[4];
#pragma unroll
    for (int mt = 0; mt < 4; ++mt)
      af[mt] = *reinterpret_cast<const short8*>(ab + mt * 512);
    ab += 8192;
    short8 bf[4];
#pragma unroll
    for (int nt = 0; nt < 4; ++nt)
      bf[nt] = *reinterpret_cast<const short8*>(ba + nt * 16 * PA);
    ba += 32;
#pragma unroll
    for (int mt = 0; mt < 4; ++mt)
#pragma unroll
      for (int nt = 0; nt < 4; ++nt)
        acc[mt][nt] = mfma16(af[mt], bf[nt], acc[mt][nt]);
  }
  if (KKB > 0) {
    const unsigned short* bb = srcB + (unsigned)(l16 * EMB_PITCH + quad * 8);
#pragma unroll
    for (int kk = 0; kk < KKB; ++kk) {
      short8 af[4];
#pragma unroll
      for (int mt = 0; mt < 4; ++mt)
        af[mt] = *reinterpret_cast<const short8*>(ab + mt * 512);
      ab += 8192;
      short8 bf[4];
#pragma unroll
      for (int nt = 0; nt < 4; ++nt)
        bf[nt] = *reinterpret_cast<const short8*>(bb + nt * 16 * EMB_PITCH);
      bb += 32;
#pragma unroll
      for (int mt = 0; mt < 4; ++mt)
#pragma unroll
        for (int nt = 0; nt < 4; ++nt)
          acc[mt][nt] = mfma16(af[mt], bf[nt], acc[mt][nt]);
    }
  }

  if (RB) __syncthreads();   // all waves done reading src (src aliases dst)
#pragma unroll
  for (int nt = 0; nt < 4; ++nt) {
    unsigned short* rowp = dst + (unsigned)((nt * 16 + l16) * ACT_PITCH);
#pragma unroll
    for (int mt = 0; mt < 4; ++mt) {
      f32x4 v = acc[mt][nt];
      uint2 pr;
      pr.x = cvtpk(fmaxf(v.x, 0.0f), fmaxf(v.y, 0.0f));
      pr.y = cvtpk(fmaxf(v.z, 0.0f), fmaxf(v.w, 0.0f));
      *reinterpret_cast<uint2*>(rowp + (unsigned)(w * 64 + mt * 16 + quad * 4)) = pr;
    }
  }
  __syncthreads();           // writes visible to all waves
}

__launch_bounds__(256, 3)
__global__ void mlp_mfma(const float* __restrict__ pts, long N,
                         BPtrs B, const float* __restrict__ b8,
                         const unsigned short* __restrict__ wpk,
                         float* __restrict__ out) {
  __shared__ unsigned short act[64 * ACT_PITCH];  // 33 KB
  __shared__ unsigned short emb[64 * EMB_PITCH];  // 9 KB
  const int tid = threadIdx.x;
  const int w = tid >> 6, lane = tid & 63;
  const int quad = lane >> 4, l16 = lane & 15;
  const long pbase = (long)blockIdx.x * 64;

  // ---- embedding: thread t -> point t/4, features (t&3)*16..+15 -----------
  {
    const int pt = tid >> 2, fg = tid & 3;
    const long pg = pbase + pt;
    float c0 = 0.f, c1 = 0.f, c2 = 0.f;
    if (pg < N) {
      const float* pp = pts + pg * 3;
      c0 = pp[0]; c1 = pp[1]; c2 = pp[2];
    }
    float x0 = c0 * INV2PI, x1 = c1 * INV2PI, x2 = c2 * INV2PI;
    unsigned pk[8];
#pragma unroll
    for (int i = 0; i < 16; i += 2) {
      int f0 = fg * 16 + i;
      float v0 = embval(f0,     c0, c1, c2, x0, x1, x2);
      float v1 = embval(f0 + 1, c0, c1, c2, x0, x1, x2);
      pk[i >> 1] = cvtpk(v0, v1);
    }
    uint4* dp = reinterpret_cast<uint4*>(emb + pt * EMB_PITCH + fg * 16);
    dp[0] = uint4{pk[0], pk[1], pk[2], pk[3]};
    dp[1] = uint4{pk[4], pk[5], pk[6], pk[7]};
  }
  __syncthreads();

  do_layer<2, EMB_PITCH, 0, false>(emb, nullptr, wpk + PK_L0, B.b[0], act, w, quad, l16);
  do_layer<8, ACT_PITCH, 0, true >(act, nullptr, wpk + PK_L1, B.b[1], act, w, quad, l16);
  do_layer<8, ACT_PITCH, 0, true >(act, nullptr, wpk + PK_L2, B.b[2], act, w, quad, l16);
  do_layer<8, ACT_PITCH, 0, true >(act, nullptr, wpk + PK_L3, B.b[3], act, w, quad, l16);
  do_layer<8, ACT_PITCH, 0, true >(act, nullptr, wpk + PK_L4, B.b[4], act, w, quad, l16);
  do_layer<8, ACT_PITCH, 2, true >(act, emb,     wpk + PK_L5, B.b[5], act, w, quad, l16);
  do_layer<8, ACT_PITCH, 0, true >(act, nullptr, wpk + PK_L6, B.b[6], act, w, quad, l16);
  do_layer<8, ACT_PITCH, 0, true >(act, nullptr, wpk + PK_L7, B.b[7], act, w, quad, l16);

  // ---- final 256->4: wave w covers points [16w, 16w+16) -------------------
  {
    const unsigned short* w8b = wpk + PK_W8 + (unsigned)(l16 * 256 + quad * 8);
    const unsigned short* ba = act + (unsigned)((w * 16 + l16) * ACT_PITCH + quad * 8);
    f32x4 acc = {0.f, 0.f, 0.f, 0.f};
#pragma unroll
    for (int kk = 0; kk < 8; ++kk) {
      short8 a = *reinterpret_cast<const short8*>(w8b + kk * 32);
      short8 b = *reinterpret_cast<const short8*>(ba + kk * 32);
      acc = mfma16(a, b, acc);
    }
    if (quad == 0) {
      f32x4 bb = *reinterpret_cast<const f32x4*>(b8);
      long pg = pbase + w * 16 + l16;
      f32x4 v = acc + bb;
      if (pg < N) *reinterpret_cast<f32x4*>(out + pg * 4) = v;
    }
  }
}

// ---------------------------------------------------------------------------
// Fallback (ws too small): round-1 VALU kernel, fp32 weights, proven correct.
// ---------------------------------------------------------------------------
__device__ __forceinline__ unsigned pk2s(float a, float b) {
  return (unsigned)f2bf(a) | ((unsigned)f2bf(b) << 16);
}
__device__ __forceinline__ void fb_seg(const unsigned short* src, int kRows,
                                       const float* __restrict__ wr,
                                       int lane, int ps, float acc[4][16]) {
#pragma unroll 4
  for (int k = 0; k < kRows; ++k) {
    const float* p = wr + k * 256 + lane;
    float w0 = p[0], w1 = p[64], w2 = p[128], w3 = p[192];
    const uint4* xr = reinterpret_cast<const uint4*>(src + ((k << 6) + ps));
    uint4 q0 = xr[0], q1 = xr[1];
    float x[16];
    x[0] = bf_lo(q0.x);  x[1] = bf_hi(q0.x);  x[2] = bf_lo(q0.y);  x[3] = bf_hi(q0.y);
    x[4] = bf_lo(q0.z);  x[5] = bf_hi(q0.z);  x[6] = bf_lo(q0.w);  x[7] = bf_hi(q0.w);
    x[8] = bf_lo(q1.x);  x[9] = bf_hi(q1.x);  x[10] = bf_lo(q1.y); x[11] = bf_hi(q1.y);
    x[12] = bf_lo(q1.z); x[13] = bf_hi(q1.z); x[14] = bf_lo(q1.w); x[15] = bf_hi(q1.w);
#pragma unroll
    for (int pp = 0; pp < 16; ++pp) {
      acc[0][pp] = fmaf(w0, x[pp], acc[0][pp]);
      acc[1][pp] = fmaf(w1, x[pp], acc[1][pp]);
      acc[2][pp] = fmaf(w2, x[pp], acc[2][pp]);
      acc[3][pp] = fmaf(w3, x[pp], acc[3][pp]);
    }
  }
}
__device__ __forceinline__ void fb_layer(const unsigned short* srcA, int kA,
                                         const unsigned short* srcB, int kB,
                                         const float* wrA, const float* wrB,
                                         const float* bias,
                                         unsigned short* dst, int lane, int ps) {
  float acc[4][16];
#pragma unroll
  for (int jt = 0; jt < 4; ++jt) {
    float bb = bias[lane + (jt << 6)];
#pragma unroll
    for (int pp = 0; pp < 16; ++pp) acc[jt][pp] = bb;
  }
  fb_seg(srcA, kA, wrA, lane, ps, acc);
  if (srcB) fb_seg(srcB, kB, wrB, lane, ps, acc);
#pragma unroll
  for (int jt = 0; jt < 4; ++jt) {
    unsigned short* dr = dst + (((lane + (jt << 6)) << 6) + ps);
    float r[16];
#pragma unroll
    for (int pp = 0; pp < 16; ++pp) r[pp] = fmaxf(acc[jt][pp], 0.0f);
    uint4 a, b;
    a.x = pk2s(r[0], r[1]);   a.y = pk2s(r[2], r[3]);
    a.z = pk2s(r[4], r[5]);   a.w = pk2s(r[6], r[7]);
    b.x = pk2s(r[8], r[9]);   b.y = pk2s(r[10], r[11]);
    b.z = pk2s(r[12], r[13]); b.w = pk2s(r[14], r[15]);
    reinterpret_cast<uint4*>(dr)[0] = a;
    reinterpret_cast<uint4*>(dr)[1] = b;
  }
}
__launch_bounds__(256, 2)
__global__ void mlp_fallback(const float* __restrict__ pts, int N,
                             WPtrs W, BPtrs B,
                             const float* __restrict__ w8,
                             const float* __restrict__ b8,
                             float* __restrict__ out) {
  __shared__ unsigned short act[256 * 64];
  __shared__ unsigned short emb[64 * 64];
  const int lane = threadIdx.x & 63;
  const int ps = (threadIdx.x >> 6) << 4;
  const long pbase = (long)blockIdx.x * 64 + ps;
#pragma unroll
  for (int i = 0; i < 16; ++i) {
    int idx = (i << 6) + lane;
    int f = idx >> 4, pp = idx & 15;
    float v = 0.0f;
    if (f < 63) {
      float c = (pbase + pp < N) ? pts[(pbase + pp) * 3 + (f / 21)] : 0.0f;
      float x = c * INV2PI;
      v = embval(f, c, c, c, x, x, x);
    }
    emb[(f << 6) + ps + pp] = f2bf(v);
  }
  fb_layer(emb, 63, nullptr, 0, W.w[0], nullptr, B.b[0], act, lane, ps);
#pragma unroll 1
  for (int l = 1; l <= 4; ++l)
    fb_layer(act, 256, nullptr, 0, W.w[l], nullptr, B.b[l], act, lane, ps);
  fb_layer(act, 256, emb, 63, W.w[5], W.w[5] + 256 * 256, B.b[5], act, lane, ps);
#pragma unroll 1
  for (int l = 6; l <= 7; ++l)
    fb_layer(act, 256, nullptr, 0, W.w[l], nullptr, B.b[l], act, lane, ps);
  {
    const int pp = lane & 15, cc = lane >> 4;
    float a = b8[cc];
#pragma unroll 4
    for (int k = 0; k < 256; ++k)
      a = fmaf(bf_lo((unsigned)act[(k << 6) + ps + pp]), w8[(k << 2) + cc], a);
    if (pbase + pp < N) out[(pbase + pp) * 4 + cc] = a;
  }
}

extern "C" void kernel_launch(void* const* d_in, const int* in_sizes, int n_in,
                              void* d_out, int out_size, void* d_ws, size_t ws_size,
                              hipStream_t stream) {
  const float* pts = (const float*)d_in[0];
  WPtrs W; BPtrs B;
  for (int i = 0; i < 8; ++i) {
    W.w[i] = (const float*)d_in[1 + 2 * i];
    B.b[i] = (const float*)d_in[2 + 2 * i];
  }
  const float* w8 = (const float*)d_in[17];
  const float* b8 = (const float*)d_in[18];
  float* out = (float*)d_out;
  const long N = in_sizes[0] / 3;

  const size_t need = (size_t)PK_TOTAL * sizeof(unsigned short);
  if (ws_size >= need) {
    unsigned short* wpk = (unsigned short*)d_ws;
    pack_weights<<<1936, 256, 0, stream>>>(W, w8, wpk);
    mlp_mfma<<<(int)((N + 63) / 64), 256, 0, stream>>>(pts, N, B, b8, wpk, out);
  } else {
    mlp_fallback<<<(int)((N + 63) / 64), 256, 0, stream>>>(pts, (int)N, W, B, w8, b8, out);
  }
}

// Round 4
// 602.876 us; speedup vs baseline: 10.1935x; 1.0302x over previous
//
#include <hip/hip_runtime.h>
#include <math.h>

// ---------------------------------------------------------------------------
// Round 4: 32x32x16 MFMA (2495 TF rate vs 2075 for 16x16x32), 4 blocks/CU.
// LDS = act 64pt x 256ch bf16 (32KB, XOR-16B-granule swizzle) + emb 64x64
// (8KB, same swizzle) = 40KB exactly -> 4 blocks/CU, 16 waves.
// Wave w: out-ch [64w,64w+64) x all 64 pts; acc = 2mt x 2nt x f32x16.
// A-pack: [kk16-block][ch 0..255][16 elems] -> one dwordx4 per frag.
// SQ_LDS_BANK_CONFLICT learned to be intrinsic to wide LDS ops (identical
// across swizzle schemes) -- ignored hereafter.
// Numerics: bf16 W+act, fp32 acc (proven absmax ~3.9e-3 vs thr 1.148e-2).
// ---------------------------------------------------------------------------

typedef __attribute__((ext_vector_type(8))) short short8;
typedef __attribute__((ext_vector_type(4))) float f32x4;
typedef __attribute__((ext_vector_type(16))) float f32x16;

struct WPtrs { const float* w[8]; };
struct BPtrs { const float* b[8]; };

#define INV2PI 0.15915494309189533577f

// kk-block (K=16) offsets in elems (kkg * 4096):
// L0: 4kk @0, L1-L4: 16kk @4/20/36/52, L5: 20kk @68, L6: 16kk @88, L7 @104.
#define PK_L0 0
#define PK_L1 16384
#define PK_L2 81920
#define PK_L3 147456
#define PK_L4 212992
#define PK_L5 278528
#define PK_L6 360448
#define PK_L7 425984
#define PK_W8 491520           // [j=0..15][k=0..255]
#define PK_TOTAL 495616

__device__ __forceinline__ unsigned short f2bf(float v) {
  unsigned u = __float_as_uint(v);
  u = u + 0x7fffu + ((u >> 16) & 1u);
  return (unsigned short)(u >> 16);
}
__device__ __forceinline__ float bf_lo(unsigned u) { return __uint_as_float(u << 16); }
__device__ __forceinline__ float bf_hi(unsigned u) { return __uint_as_float(u & 0xffff0000u); }

__device__ __forceinline__ unsigned cvtpk(float a, float b) {
#if __has_builtin(__builtin_amdgcn_cvt_pk_bf16_f32)
  typedef __attribute__((ext_vector_type(2))) __bf16 bf16x2_t;
  bf16x2_t r = __builtin_amdgcn_cvt_pk_bf16_f32(a, b);
  return __builtin_bit_cast(unsigned, r);
#else
  unsigned ua = __float_as_uint(a);
  ua += 0x7fffu + ((ua >> 16) & 1u);
  unsigned ub = __float_as_uint(b);
  ub += 0x7fffu + ((ub >> 16) & 1u);
#if __has_builtin(__builtin_amdgcn_perm)
  return __builtin_amdgcn_perm(ub, ua, 0x07060302u);
#else
  return (ua >> 16) | (ub & 0xffff0000u);
#endif
#endif
}

__device__ __forceinline__ float fractf_(float x) {
#if __has_builtin(__builtin_amdgcn_fract_f32)
  return __builtin_amdgcn_fract_f32(x);
#else
  return x - floorf(x);
#endif
}
__device__ __forceinline__ float sin_rev(float rev) {
#if __has_builtin(__builtin_amdgcn_sinf)
  return __builtin_amdgcn_sinf(rev);
#else
  return __sinf(rev * 6.283185307179586f);
#endif
}

__device__ __forceinline__ float embval(int f, float c0, float c1, float c2,
                                        float x0, float x1, float x2) {
  if (f >= 63) return 0.0f;
  int d = (f >= 21 ? 1 : 0) + (f >= 42 ? 1 : 0);
  int r = f - d * 21;
  float c = (d == 0) ? c0 : (d == 1 ? c1 : c2);
  float x = (d == 0) ? x0 : (d == 1 ? x1 : x2);
  bool isc = r > 10;
  int e = isc ? (r - 11) : (r - 1);
  float rev = fractf_(ldexpf(x, e) + (isc ? 0.25f : 0.0f));
  float s = sin_rev(rev);
  return (r == 0) ? c : s;
}

__device__ __forceinline__ f32x16 mfma32(short8 a, short8 b, f32x16 c) {
  return __builtin_amdgcn_mfma_f32_32x32x16_bf16(a, b, c, 0, 0, 0);
}
__device__ __forceinline__ f32x4 mfma16(short8 a, short8 b, f32x4 c) {
  return __builtin_amdgcn_mfma_f32_16x16x32_bf16(a, b, c, 0, 0, 0);
}

// ---------------------------------------------------------------------------
// Prologue: pack weights as [kk][ch 0..255][16] bf16 (+ W8 as [j16][k256]).
// ---------------------------------------------------------------------------
__global__ void pack_weights(WPtrs W, const float* __restrict__ w8,
                             unsigned short* __restrict__ out) {
  int idx = blockIdx.x * 256 + threadIdx.x;
  if (idx >= PK_TOTAL) return;
  float v;
  if (idx >= PK_W8) {
    int t = idx - PK_W8;
    int j = t >> 8, k = t & 255;
    v = (j < 4) ? w8[k * 4 + j] : 0.0f;
  } else {
    int e = idx & 15;
    int blk = idx >> 4;
    int ch = blk & 255;
    int kkg = blk >> 8;              // 0..119
    int l, kk0;
    if      (kkg < 4)   { l = 0; kk0 = 0;   }
    else if (kkg < 20)  { l = 1; kk0 = 4;   }
    else if (kkg < 36)  { l = 2; kk0 = 20;  }
    else if (kkg < 52)  { l = 3; kk0 = 36;  }
    else if (kkg < 68)  { l = 4; kk0 = 52;  }
    else if (kkg < 88)  { l = 5; kk0 = 68;  }
    else if (kkg < 104) { l = 6; kk0 = 88;  }
    else                { l = 7; kk0 = 104; }
    int k = (kkg - kk0) * 16 + e;
    const int realK[8] = {63, 256, 256, 256, 256, 319, 256, 256};
    v = (k < realK[l]) ? W.w[l][k * 256 + ch] : 0.0f;
  }
  out[idx] = f2bf(v);
}

// ---------------------------------------------------------------------------
// One layer via 32x32x16. srcA rows PAB bytes (XOR-swizzled 16B granules),
// KKB extra kk-blocks from emb (128B rows). RB: barrier before writeback
// (src aliases dst).
// ---------------------------------------------------------------------------
template <int KKA, int PAB, int KKB, bool RB>
__device__ __forceinline__ void do_layer32(
    const unsigned short* srcA, const unsigned short* srcB,
    const unsigned short* __restrict__ wblk,
    const float* __restrict__ bias,
    unsigned short* dst, int w, int n, int h, unsigned swz) {
  f32x16 acc[2][2];
#pragma unroll
  for (int mt = 0; mt < 2; ++mt)
#pragma unroll
    for (int q = 0; q < 4; ++q) {
      f32x4 bq = *reinterpret_cast<const f32x4*>(bias + w * 64 + mt * 32 + q * 8 + h * 4);
#pragma unroll
      for (int r = 0; r < 4; ++r) {
        acc[mt][0][q * 4 + r] = bq[r];
        acc[mt][1][q * 4 + r] = bq[r];
      }
    }

  const unsigned short* ab = wblk + (unsigned)((w * 64 + n) * 16 + h * 8);
  const char* rA0 = (const char*)srcA + (unsigned)(n * PAB);
  const char* rA1 = rA0 + 32 * PAB;

#pragma unroll 4
  for (int kk = 0; kk < KKA; ++kk) {
    short8 a0 = *reinterpret_cast<const short8*>(ab + kk * 4096);
    short8 a1 = *reinterpret_cast<const short8*>(ab + kk * 4096 + 512);
    unsigned off = ((unsigned)(kk * 32 + h * 16)) ^ swz;
    short8 b0 = *reinterpret_cast<const short8*>(rA0 + off);
    short8 b1 = *reinterpret_cast<const short8*>(rA1 + off);
    acc[0][0] = mfma32(a0, b0, acc[0][0]);
    acc[0][1] = mfma32(a0, b1, acc[0][1]);
    acc[1][0] = mfma32(a1, b0, acc[1][0]);
    acc[1][1] = mfma32(a1, b1, acc[1][1]);
  }
  if (KKB > 0) {
    const char* rB0 = (const char*)srcB + (unsigned)(n * 128);
    const char* rB1 = rB0 + 32 * 128;
#pragma unroll
    for (int kl = 0; kl < KKB; ++kl) {
      const unsigned short* ab2 = ab + (KKA + kl) * 4096;
      short8 a0 = *reinterpret_cast<const short8*>(ab2);
      short8 a1 = *reinterpret_cast<const short8*>(ab2 + 512);
      unsigned off = ((unsigned)(kl * 32 + h * 16)) ^ swz;
      short8 b0 = *reinterpret_cast<const short8*>(rB0 + off);
      short8 b1 = *reinterpret_cast<const short8*>(rB1 + off);
      acc[0][0] = mfma32(a0, b0, acc[0][0]);
      acc[0][1] = mfma32(a0, b1, acc[0][1]);
      acc[1][0] = mfma32(a1, b0, acc[1][0]);
      acc[1][1] = mfma32(a1, b1, acc[1][1]);
    }
  }

  if (RB) __syncthreads();   // all waves done reading src (aliases dst)
#pragma unroll
  for (int nt = 0; nt < 2; ++nt) {
    char* rowp = (char*)dst + (unsigned)((nt * 32 + n) * 512);
#pragma unroll
    for (int mt = 0; mt < 2; ++mt)
#pragma unroll
      for (int q = 0; q < 4; ++q) {
        float x0 = fmaxf(acc[mt][nt][q * 4 + 0], 0.0f);
        float x1 = fmaxf(acc[mt][nt][q * 4 + 1], 0.0f);
        float x2 = fmaxf(acc[mt][nt][q * 4 + 2], 0.0f);
        float x3 = fmaxf(acc[mt][nt][q * 4 + 3], 0.0f);
        uint2 pr;
        pr.x = cvtpk(x0, x1);
        pr.y = cvtpk(x2, x3);
        unsigned off = ((unsigned)(w * 128 + mt * 64 + q * 16 + h * 8)) ^ swz;
        *reinterpret_cast<uint2*>(rowp + off) = pr;
      }
  }
  __syncthreads();           // writes visible
}

__launch_bounds__(256, 4)
__global__ void mlp_mfma(const float* __restrict__ pts, long N,
                         BPtrs B, const float* __restrict__ b8,
                         const unsigned short* __restrict__ wpk,
                         float* __restrict__ out) {
  __shared__ unsigned short act[64 * 256];  // 32 KB, [pt][ch] swizzled
  __shared__ unsigned short emb[64 * 64];   // 8 KB,  [pt][f]  swizzled
  const int tid = threadIdx.x;
  const int w = tid >> 6, lane = tid & 63;
  const int n = lane & 31, h = lane >> 5;
  const unsigned swz = (unsigned)((n & 7) << 4);   // == (pt&7)<<4 for this lane
  const long pbase = (long)blockIdx.x * 64;

  // ---- embedding: thread t -> point t/4, features (t&3)*16..+15 -----------
  {
    const int pt = tid >> 2, fg = tid & 3;
    const long pg = pbase + pt;
    float c0 = 0.f, c1 = 0.f, c2 = 0.f;
    if (pg < N) {
      const float* pp = pts + pg * 3;
      c0 = pp[0]; c1 = pp[1]; c2 = pp[2];
    }
    float x0 = c0 * INV2PI, x1 = c1 * INV2PI, x2 = c2 * INV2PI;
    unsigned pk[8];
#pragma unroll
    for (int i = 0; i < 16; i += 2) {
      int f0 = fg * 16 + i;
      float v0 = embval(f0,     c0, c1, c2, x0, x1, x2);
      float v1 = embval(f0 + 1, c0, c1, c2, x0, x1, x2);
      pk[i >> 1] = cvtpk(v0, v1);
    }
    const unsigned sw = (unsigned)((pt & 7) << 4);
    char* rowp = (char*)emb + (unsigned)(pt * 128);
    *reinterpret_cast<uint4*>(rowp + (((unsigned)(fg * 32)) ^ sw)) =
        uint4{pk[0], pk[1], pk[2], pk[3]};
    *reinterpret_cast<uint4*>(rowp + (((unsigned)(fg * 32 + 16)) ^ sw)) =
        uint4{pk[4], pk[5], pk[6], pk[7]};
  }
  __syncthreads();

  do_layer32<4,  128, 0, false>(emb, nullptr, wpk + PK_L0, B.b[0], act, w, n, h, swz);
  do_layer32<16, 512, 0, true >(act, nullptr, wpk + PK_L1, B.b[1], act, w, n, h, swz);
  do_layer32<16, 512, 0, true >(act, nullptr, wpk + PK_L2, B.b[2], act, w, n, h, swz);
  do_layer32<16, 512, 0, true >(act, nullptr, wpk + PK_L3, B.b[3], act, w, n, h, swz);
  do_layer32<16, 512, 0, true >(act, nullptr, wpk + PK_L4, B.b[4], act, w, n, h, swz);
  do_layer32<16, 512, 4, true >(act, emb,     wpk + PK_L5, B.b[5], act, w, n, h, swz);
  do_layer32<16, 512, 0, true >(act, nullptr, wpk + PK_L6, B.b[6], act, w, n, h, swz);
  do_layer32<16, 512, 0, true >(act, nullptr, wpk + PK_L7, B.b[7], act, w, n, h, swz);

  // ---- final 256->4 via 16x16x32 (proven in r3): wave w -> pts [16w,16w+16)
  {
    const int l16 = lane & 15, quad = lane >> 4;
    const unsigned short* w8b = wpk + PK_W8 + (unsigned)(l16 * 256 + quad * 8);
    const int pt = w * 16 + l16;
    const char* ba = (const char*)act + (unsigned)(pt * 512);
    f32x4 a4 = {0.f, 0.f, 0.f, 0.f};
#pragma unroll
    for (int kk = 0; kk < 8; ++kk) {
      short8 a = *reinterpret_cast<const short8*>(w8b + kk * 32);
      unsigned off = ((unsigned)(kk * 64 + quad * 16)) ^ swz;  // swz==(pt&7)<<4 here
      short8 b = *reinterpret_cast<const short8*>(ba + off);
      a4 = mfma16(a, b, a4);
    }
    if (quad == 0) {
      f32x4 bb = *reinterpret_cast<const f32x4*>(b8);
      long pg = pbase + pt;
      f32x4 v = a4 + bb;
      if (pg < N) *reinterpret_cast<f32x4*>(out + pg * 4) = v;
    }
  }
}

// ---------------------------------------------------------------------------
// Fallback (ws too small): round-1 VALU kernel, fp32 weights, proven correct.
// ---------------------------------------------------------------------------
__device__ __forceinline__ unsigned pk2s(float a, float b) {
  return (unsigned)f2bf(a) | ((unsigned)f2bf(b) << 16);
}
__device__ __forceinline__ void fb_seg(const unsigned short* src, int kRows,
                                       const float* __restrict__ wr,
                                       int lane, int ps, float acc[4][16]) {
#pragma unroll 4
  for (int k = 0; k < kRows; ++k) {
    const float* p = wr + k * 256 + lane;
    float w0 = p[0], w1 = p[64], w2 = p[128], w3 = p[192];
    const uint4* xr = reinterpret_cast<const uint4*>(src + ((k << 6) + ps));
    uint4 q0 = xr[0], q1 = xr[1];
    float x[16];
    x[0] = bf_lo(q0.x);  x[1] = bf_hi(q0.x);  x[2] = bf_lo(q0.y);  x[3] = bf_hi(q0.y);
    x[4] = bf_lo(q0.z);  x[5] = bf_hi(q0.z);  x[6] = bf_lo(q0.w);  x[7] = bf_hi(q0.w);
    x[8] = bf_lo(q1.x);  x[9] = bf_hi(q1.x);  x[10] = bf_lo(q1.y); x[11] = bf_hi(q1.y);
    x[12] = bf_lo(q1.z); x[13] = bf_hi(q1.z); x[14] = bf_lo(q1.w); x[15] = bf_hi(q1.w);
#pragma unroll
    for (int pp = 0; pp < 16; ++pp) {
      acc[0][pp] = fmaf(w0, x[pp], acc[0][pp]);
      acc[1][pp] = fmaf(w1, x[pp], acc[1][pp]);
      acc[2][pp] = fmaf(w2, x[pp], acc[2][pp]);
      acc[3][pp] = fmaf(w3, x[pp], acc[3][pp]);
    }
  }
}
__device__ __forceinline__ void fb_layer(const unsigned short* srcA, int kA,
                                         const unsigned short* srcB, int kB,
                                         const float* wrA, const float* wrB,
                                         const float* bias,
                                         unsigned short* dst, int lane, int ps) {
  float acc[4][16];
#pragma unroll
  for (int jt = 0; jt < 4; ++jt) {
    float bb = bias[lane + (jt << 6)];
#pragma unroll
    for (int pp = 0; pp < 16; ++pp) acc[jt][pp] = bb;
  }
  fb_seg(srcA, kA, wrA, lane, ps, acc);
  if (srcB) fb_seg(srcB, kB, wrB, lane, ps, acc);
#pragma unroll
  for (int jt = 0; jt < 4; ++jt) {
    unsigned short* dr = dst + (((lane + (jt << 6)) << 6) + ps);
    float r[16];
#pragma unroll
    for (int pp = 0; pp < 16; ++pp) r[pp] = fmaxf(acc[jt][pp], 0.0f);
    uint4 a, b;
    a.x = pk2s(r[0], r[1]);   a.y = pk2s(r[2], r[3]);
    a.z = pk2s(r[4], r[5]);   a.w = pk2s(r[6], r[7]);
    b.x = pk2s(r[8], r[9]);   b.y = pk2s(r[10], r[11]);
    b.z = pk2s(r[12], r[13]); b.w = pk2s(r[14], r[15]);
    reinterpret_cast<uint4*>(dr)[0] = a;
    reinterpret_cast<uint4*>(dr)[1] = b;
  }
}
__launch_bounds__(256, 2)
__global__ void mlp_fallback(const float* __restrict__ pts, int N,
                             WPtrs W, BPtrs B,
                             const float* __restrict__ w8,
                             const float* __restrict__ b8,
                             float* __restrict__ out) {
  __shared__ unsigned short act[256 * 64];
  __shared__ unsigned short emb[64 * 64];
  const int lane = threadIdx.x & 63;
  const int ps = (threadIdx.x >> 6) << 4;
  const long pbase = (long)blockIdx.x * 64 + ps;
#pragma unroll
  for (int i = 0; i < 16; ++i) {
    int idx = (i << 6) + lane;
    int f = idx >> 4, pp = idx & 15;
    float v = 0.0f;
    if (f < 63) {
      float c = (pbase + pp < N) ? pts[(pbase + pp) * 3 + (f / 21)] : 0.0f;
      float x = c * INV2PI;
      v = embval(f, c, c, c, x, x, x);
    }
    emb[(f << 6) + ps + pp] = f2bf(v);
  }
  fb_layer(emb, 63, nullptr, 0, W.w[0], nullptr, B.b[0], act, lane, ps);
#pragma unroll 1
  for (int l = 1; l <= 4; ++l)
    fb_layer(act, 256, nullptr, 0, W.w[l], nullptr, B.b[l], act, lane, ps);
  fb_layer(act, 256, emb, 63, W.w[5], W.w[5] + 256 * 256, B.b[5], act, lane, ps);
#pragma unroll 1
  for (int l = 6; l <= 7; ++l)
    fb_layer(act, 256, nullptr, 0, W.w[l], nullptr, B.b[l], act, lane, ps);
  {
    const int pp = lane & 15, cc = lane >> 4;
    float a = b8[cc];
#pragma unroll 4
    for (int k = 0; k < 256; ++k)
      a = fmaf(bf_lo((unsigned)act[(k << 6) + ps + pp]), w8[(k << 2) + cc], a);
    if (pbase + pp < N) out[(pbase + pp) * 4 + cc] = a;
  }
}

extern "C" void kernel_launch(void* const* d_in, const int* in_sizes, int n_in,
                              void* d_out, int out_size, void* d_ws, size_t ws_size,
                              hipStream_t stream) {
  const float* pts = (const float*)d_in[0];
  WPtrs W; BPtrs B;
  for (int i = 0; i < 8; ++i) {
    W.w[i] = (const float*)d_in[1 + 2 * i];
    B.b[i] = (const float*)d_in[2 + 2 * i];
  }
  const float* w8 = (const float*)d_in[17];
  const float* b8 = (const float*)d_in[18];
  float* out = (float*)d_out;
  const long N = in_sizes[0] / 3;

  const size_t need = (size_t)PK_TOTAL * sizeof(unsigned short);
  if (ws_size >= need) {
    unsigned short* wpk = (unsigned short*)d_ws;
    pack_weights<<<1936, 256, 0, stream>>>(W, w8, wpk);
    mlp_mfma<<<(int)((N + 63) / 64), 256, 0, stream>>>(pts, N, B, b8, wpk, out);
  } else {
    mlp_fallback<<<(int)((N + 63) / 64), 256, 0, stream>>>(pts, (int)N, W, B, w8, b8, out);
  }
}